// Round 1
// baseline (639.201 us; speedup 1.0000x reference)
//
#include <hip/hip_runtime.h>

#define N_NODES 25000
#define N_EDGES 400000

// ---------------- fast transcendentals (fp32, ~2ulp) ----------------
__device__ __forceinline__ float fast_sigmoid(float x) {
    return __builtin_amdgcn_rcpf(1.0f + __expf(-x));
}
__device__ __forceinline__ float fast_tanh(float x) {
    return 1.0f - 2.0f * __builtin_amdgcn_rcpf(__expf(2.0f * x) + 1.0f);
}

// lane j receives value from lane j^k within its 32-lane half (k<16 keeps it
// inside the 16-lane node group). BitMode offset = (xor<<10)|(or<<5)|and.
#define SWZF(x, k) __int_as_float(__builtin_amdgcn_ds_swizzle(__float_as_int(x), ((k) << 10) | 0x1F))

// ---------------- K1: hidden0 = nf @ W_init + b_init ; copy; zero cnt --------
__global__ void __launch_bounds__(256) k_init(
        const float* __restrict__ nf, const float* __restrict__ Wini,
        const float* __restrict__ bini,
        float* __restrict__ hidden0, float* __restrict__ hid,
        int* __restrict__ cnt)
{
    int gtid = blockIdx.x * 256 + threadIdx.x;
    if (gtid <= N_NODES) cnt[gtid] = 0;
    int node = gtid >> 4;
    int j = gtid & 15;
    if (node >= N_NODES) return;

    const float4* nf4 = (const float4*)(nf + node * 32);
    float acc = bini[j];
#pragma unroll
    for (int g = 0; g < 8; ++g) {
        float4 v = nf4[g];
        acc = fmaf(v.x, Wini[(g*4+0)*16 + j], acc);
        acc = fmaf(v.y, Wini[(g*4+1)*16 + j], acc);
        acc = fmaf(v.z, Wini[(g*4+2)*16 + j], acc);
        acc = fmaf(v.w, Wini[(g*4+3)*16 + j], acc);
    }
    hidden0[node*16 + j] = acc;
    hid[node*16 + j] = acc;
}

// ---------------- CSR builds ----------------
__global__ void __launch_bounds__(256) k_hist(const int* __restrict__ idx,
                                              int* __restrict__ cnt)
{
    int e = blockIdx.x * 256 + threadIdx.x;
    if (e < N_EDGES) atomicAdd(&cnt[idx[e]], 1);
}

__global__ void __launch_bounds__(1024) k_scan(const int* __restrict__ cnt,
        int* __restrict__ row_ptr, int* __restrict__ cursor,
        float* __restrict__ out)
{
    __shared__ int sums[1024];
    int t = threadIdx.x;
    const int CH = (N_NODES + 1023) / 1024 + 1;   // 25 -> covers 25600
    int base = t * CH;
    int s = 0;
    for (int i = 0; i < CH; ++i) {
        int idx = base + i;
        if (idx < N_NODES) s += cnt[idx];
    }
    sums[t] = s;
    __syncthreads();
    for (int off = 1; off < 1024; off <<= 1) {
        int add = (t >= off) ? sums[t - off] : 0;
        __syncthreads();
        sums[t] += add;
        __syncthreads();
    }
    int run = sums[t] - s;
    for (int i = 0; i < CH; ++i) {
        int idx = base + i;
        if (idx < N_NODES) {
            row_ptr[idx] = run;
            cursor[idx]  = run;
            run += cnt[idx];
        }
    }
    if (t == 0) { row_ptr[N_NODES] = N_EDGES; out[0] = 0.0f; }
}

// sender-CSR: eids[pos] = original edge id, pos in sender-major order
__global__ void __launch_bounds__(256) k_scatter(const int* __restrict__ send,
        int* __restrict__ cursor, int* __restrict__ eids)
{
    int e = blockIdx.x * 256 + threadIdx.x;
    if (e < N_EDGES) {
        int pos = atomicAdd(&cursor[send[e]], 1);
        eids[pos] = e;
    }
}

// receiver-CSR over sender-order positions: rpos[p] = sender-order pos
__global__ void __launch_bounds__(256) k_rscatter(const int* __restrict__ eids,
        const int* __restrict__ recv,
        int* __restrict__ rcur, int* __restrict__ rpos)
{
    int pos = blockIdx.x * 256 + threadIdx.x;
    if (pos < N_EDGES) {
        int e = eids[pos];
        int r = recv[e];
        int p = atomicAdd(&rcur[r], 1);
        rpos[p] = pos;
    }
}

// ---------------- K3: sender-major message compute (NO atomics) ----------------
// group (16 lanes) = one sender s; lane = message dim m.
// q[f] = sum_h We[f, m*16+h] * h[s,h]  (We is 17KB -> L1-resident)
// per out-edge: tmp[pos*16+m] = qb + sum_f ef[eids[pos],f]*q[f]  (plain store)
__global__ void __launch_bounds__(256) k_msg(
        const float* __restrict__ hid, const float* __restrict__ ef,
        const int* __restrict__ eids,
        const float* __restrict__ We, const float* __restrict__ be,
        const int* __restrict__ row_ptr,
        float* __restrict__ tmp)
{
    int gtid = blockIdx.x * 256 + threadIdx.x;
    int s = gtid >> 4;
    int m = gtid & 15;
    if (s >= N_NODES) return;

    float h[16];
    {
        const float4* h4 = (const float4*)(hid + s*16);
        float4 a = h4[0], b = h4[1], c = h4[2], d = h4[3];
        h[0]=a.x; h[1]=a.y; h[2]=a.z;  h[3]=a.w;
        h[4]=b.x; h[5]=b.y; h[6]=b.z;  h[7]=b.w;
        h[8]=c.x; h[9]=c.y; h[10]=c.z; h[11]=c.w;
        h[12]=d.x; h[13]=d.y; h[14]=d.z; h[15]=d.w;
    }
    float q[16];
#pragma unroll
    for (int f = 0; f < 16; ++f) {
        const float4* wf = (const float4*)(We + f*256 + m*16);
        float4 a = wf[0], b = wf[1], c = wf[2], d = wf[3];
        float acc;
        acc  = a.x*h[0]  + a.y*h[1]  + a.z*h[2]  + a.w*h[3];
        acc += b.x*h[4]  + b.y*h[5]  + b.z*h[6]  + b.w*h[7];
        acc += c.x*h[8]  + c.y*h[9]  + c.z*h[10] + c.w*h[11];
        acc += d.x*h[12] + d.y*h[13] + d.z*h[14] + d.w*h[15];
        q[f] = acc;
    }
    float qb;
    {
        const float4* bf = (const float4*)(be + m*16);
        float4 a = bf[0], b = bf[1], c = bf[2], d = bf[3];
        qb  = a.x*h[0]  + a.y*h[1]  + a.z*h[2]  + a.w*h[3];
        qb += b.x*h[4]  + b.y*h[5]  + b.z*h[6]  + b.w*h[7];
        qb += c.x*h[8]  + c.y*h[9]  + c.z*h[10] + c.w*h[11];
        qb += d.x*h[12] + d.y*h[13] + d.z*h[14] + d.w*h[15];
    }

    int beg = row_ptr[s];
    int end = row_ptr[s + 1];
    for (int i = beg; i < end; ++i) {
        int e = eids[i];
        const float4* e4 = (const float4*)(ef + (size_t)e*16);
        float4 e0 = e4[0], e1 = e4[1], e2 = e4[2], e3 = e4[3];
        float a = qb;
        a = fmaf(e0.x, q[0],  a);
        a = fmaf(e0.y, q[1],  a);
        a = fmaf(e0.z, q[2],  a);
        a = fmaf(e0.w, q[3],  a);
        a = fmaf(e1.x, q[4],  a);
        a = fmaf(e1.y, q[5],  a);
        a = fmaf(e1.z, q[6],  a);
        a = fmaf(e1.w, q[7],  a);
        a = fmaf(e2.x, q[8],  a);
        a = fmaf(e2.y, q[9],  a);
        a = fmaf(e2.z, q[10], a);
        a = fmaf(e2.w, q[11], a);
        a = fmaf(e3.x, q[12], a);
        a = fmaf(e3.y, q[13], a);
        a = fmaf(e3.z, q[14], a);
        a = fmaf(e3.w, q[15], a);
        tmp[(size_t)i*16 + m] = a;
    }
}

// ---------------- K4: gather + GRU over seq=[hid||gathered msgs] (T=32) -------
// 16 lanes per node, lane j = GRU unit j. h broadcast via ds_swizzle XOR
// (no LDS memory, no barrier): lane j holds h[j^k], weights pre-permuted.
__global__ void __launch_bounds__(256) k_gru(
        const float* __restrict__ hid_in, const float* __restrict__ tmp,
        const int* __restrict__ rrow_ptr, const int* __restrict__ rpos,
        const float* __restrict__ Wi, const float* __restrict__ Wh,
        const float* __restrict__ bi, const float* __restrict__ bh,
        float* __restrict__ hid_out)
{
    int gtid = blockIdx.x * 256 + threadIdx.x;
    int node = gtid >> 4;
    int j = gtid & 15;
    if (node >= N_NODES) return;

    float x[32];
    // ---- gather messages (latency-heavy, issue first) ----
#pragma unroll
    for (int k = 0; k < 16; ++k) x[16 + k] = 0.0f;
    {
        int beg = rrow_ptr[node];
        int end = rrow_ptr[node + 1];
        for (int i = beg; i < end; ++i) {
            const float4* t4 = (const float4*)(tmp + (size_t)rpos[i]*16);
            float4 a = t4[0], b = t4[1], c = t4[2], d = t4[3];
            x[16]+=a.x; x[17]+=a.y; x[18]+=a.z; x[19]+=a.w;
            x[20]+=b.x; x[21]+=b.y; x[22]+=b.z; x[23]+=b.w;
            x[24]+=c.x; x[25]+=c.y; x[26]+=c.z; x[27]+=c.w;
            x[28]+=d.x; x[29]+=d.y; x[30]+=d.z; x[31]+=d.w;
        }
    }
    {
        const float4* a4 = (const float4*)(hid_in + node * 16);
#pragma unroll
        for (int g = 0; g < 4; ++g) {
            float4 v = a4[g];
            x[g*4+0]=v.x; x[g*4+1]=v.y; x[g*4+2]=v.z; x[g*4+3]=v.w;
        }
    }

    float Wz[16], Wr[16], Wc[16];
#pragma unroll
    for (int k = 0; k < 16; ++k) {
        int l = j ^ k;
        Wz[k] = Wh[l*48 + j];
        Wr[k] = Wh[l*48 + 16 + j];
        Wc[k] = Wh[l*48 + 32 + j];
    }
    float Wiz = Wi[j], Wir = Wi[16+j], Wih = Wi[32+j];
    float cz   = bi[j] + bh[j];
    float cr   = bi[16+j] + bh[16+j];
    float bih_ = bi[32+j];
    float bhh_ = bh[32+j];

    float hn = 0.0f;

#define STEPK(k) { float v = SWZF(hn, k); \
        az = fmaf(v, Wz[k], az); ar = fmaf(v, Wr[k], ar); ac = fmaf(v, Wc[k], ac); }

#pragma unroll
    for (int t = 0; t < 32; ++t) {
        float xv = x[t];
        float az = fmaf(xv, Wiz, cz);
        float ar = fmaf(xv, Wir, cr);
        float ac = bhh_;
        az = fmaf(hn, Wz[0], az);
        ar = fmaf(hn, Wr[0], ar);
        ac = fmaf(hn, Wc[0], ac);
        STEPK(1)  STEPK(2)  STEPK(3)  STEPK(4)  STEPK(5)
        STEPK(6)  STEPK(7)  STEPK(8)  STEPK(9)  STEPK(10)
        STEPK(11) STEPK(12) STEPK(13) STEPK(14) STEPK(15)
        float z  = fast_sigmoid(az);
        float r  = fast_sigmoid(ar);
        float hc = fast_tanh(fmaf(xv, Wih, bih_) + r * ac);
        hn = fmaf(z, hn - hc, hc);   // z*h + (1-z)*hc
    }
#undef STEPK
    hid_out[node*16 + j] = hn;
}

// ---------------- K5: readout ----------------
__global__ void __launch_bounds__(256) k_readout(
        const float* __restrict__ hid, const float* __restrict__ hid0,
        const float* __restrict__ Wri, const float* __restrict__ bri,
        const float* __restrict__ Wrj, const float* __restrict__ brj,
        float* __restrict__ out)
{
    int n = blockIdx.x * 256 + threadIdx.x;
    float val = 0.0f;
    if (n < N_NODES) {
        const float4* h4 = (const float4*)(hid + n * 16);
        const float4* g4 = (const float4*)(hid0 + n * 16);
        float iv = bri[0];
        float jv = brj[0];
#pragma unroll
        for (int g = 0; g < 4; ++g) {
            float4 h  = h4[g];
            float4 h0 = g4[g];
            iv = fmaf(h.x,  Wri[g*4+0], iv);  iv = fmaf(h.y,  Wri[g*4+1], iv);
            iv = fmaf(h.z,  Wri[g*4+2], iv);  iv = fmaf(h.w,  Wri[g*4+3], iv);
            iv = fmaf(h0.x, Wri[16+g*4+0], iv); iv = fmaf(h0.y, Wri[16+g*4+1], iv);
            iv = fmaf(h0.z, Wri[16+g*4+2], iv); iv = fmaf(h0.w, Wri[16+g*4+3], iv);
            jv = fmaf(h.x,  Wrj[g*4+0], jv);  jv = fmaf(h.y,  Wrj[g*4+1], jv);
            jv = fmaf(h.z,  Wrj[g*4+2], jv);  jv = fmaf(h.w,  Wrj[g*4+3], jv);
        }
        val = iv * jv;
    }
#pragma unroll
    for (int off = 32; off > 0; off >>= 1)
        val += __shfl_xor(val, off, 64);
    __shared__ float wsum[4];
    int w = threadIdx.x >> 6;
    if ((threadIdx.x & 63) == 0) wsum[w] = val;
    __syncthreads();
    if (threadIdx.x == 0)
        atomicAdd(out, wsum[0] + wsum[1] + wsum[2] + wsum[3]);
}

// ---------------- launch ----------------
extern "C" void kernel_launch(void* const* d_in, const int* in_sizes, int n_in,
                              void* d_out, int out_size, void* d_ws, size_t ws_size,
                              hipStream_t stream)
{
    const float* node_features = (const float*)d_in[0];
    const float* edge_features = (const float*)d_in[1];
    const float* W_init = (const float*)d_in[2];
    const float* b_init = (const float*)d_in[3];
    const float* W_edge = (const float*)d_in[4];
    const float* b_edge = (const float*)d_in[5];
    const float* Wi_gru = (const float*)d_in[6];
    const float* Wh_gru = (const float*)d_in[7];
    const float* bi_gru = (const float*)d_in[8];
    const float* bh_gru = (const float*)d_in[9];
    const float* W_ri = (const float*)d_in[10];
    const float* b_ri = (const float*)d_in[11];
    const float* W_rj = (const float*)d_in[12];
    const float* b_rj = (const float*)d_in[13];
    const int* receivers = (const int*)d_in[14];
    const int* senders   = (const int*)d_in[15];
    float* out = (float*)d_out;

    // workspace carve: floats then ints; ~34.2 MB total
    float* fb      = (float*)d_ws;
    float* hidden0 = fb;                 // 400000
    float* hidA    = fb + 400000;        // 400000
    float* hidB    = fb + 800000;        // 400000
    float* tmp     = fb + 1200000;       // 6400000 (E*16, per-edge messages)
    int* ib       = (int*)(fb + 7600000);
    int* cnt      = ib;                  // 25024
    int* row_ptr  = ib + 25024;          // 25024
    int* cursor   = ib + 50048;          // 25024
    int* rcnt     = ib + 75072;          // 25024
    int* rrow_ptr = ib + 100096;         // 25024
    int* rcur     = ib + 125120;         // 25024
    int* eids     = ib + 150144;         // 400000
    int* rpos     = ib + 550144;         // 400000

    dim3 b256(256);
    int grid_n16 = (N_NODES * 16 + 255) / 256;   // 1563
    int grid_e   = (N_EDGES + 255) / 256;        // 1563
    int grid_n   = (N_NODES + 255) / 256;        // 98

    hipMemsetAsync(rcnt, 0, 25024 * sizeof(int), stream);
    k_init<<<grid_n16, b256, 0, stream>>>(node_features, W_init, b_init,
                                          hidden0, hidA, cnt);
    k_hist<<<grid_e, b256, 0, stream>>>(senders, cnt);
    k_scan<<<1, 1024, 0, stream>>>(cnt, row_ptr, cursor, out);
    k_scatter<<<grid_e, b256, 0, stream>>>(senders, cursor, eids);
    k_hist<<<grid_e, b256, 0, stream>>>(receivers, rcnt);
    k_scan<<<1, 1024, 0, stream>>>(rcnt, rrow_ptr, rcur, out);
    k_rscatter<<<grid_e, b256, 0, stream>>>(eids, receivers, rcur, rpos);

    float* hin = hidA;
    float* hout = hidB;
    for (int it = 0; it < 3; ++it) {
        k_msg<<<grid_n16, b256, 0, stream>>>(hin, edge_features, eids,
                                             W_edge, b_edge, row_ptr, tmp);
        k_gru<<<grid_n16, b256, 0, stream>>>(hin, tmp, rrow_ptr, rpos,
                                             Wi_gru, Wh_gru, bi_gru, bh_gru, hout);
        float* t = hin; hin = hout; hout = t;
    }

    k_readout<<<grid_n, b256, 0, stream>>>(hin, hidden0, W_ri, b_ri, W_rj, b_rj, out);
}

// Round 2
// 581.064 us; speedup vs baseline: 1.1001x; 1.1001x over previous
//
#include <hip/hip_runtime.h>

#define N_NODES 25000
#define N_EDGES 400000

// ---------------- fast transcendentals (fp32, ~2ulp) ----------------
__device__ __forceinline__ float fast_sigmoid(float x) {
    return __builtin_amdgcn_rcpf(1.0f + __expf(-x));
}
__device__ __forceinline__ float fast_tanh(float x) {
    return 1.0f - 2.0f * __builtin_amdgcn_rcpf(__expf(2.0f * x) + 1.0f);
}

// lane j receives value from lane j^k within its 32-lane half (k<16 keeps it
// inside the 16-lane node group). BitMode offset = (xor<<10)|(or<<5)|and.
#define SWZF(x, k) __int_as_float(__builtin_amdgcn_ds_swizzle(__float_as_int(x), ((k) << 10) | 0x1F))
// broadcast lane t of each 16-lane group: src = (lane & 0x10) | t
#define BCAST16(x, t) __int_as_float(__builtin_amdgcn_ds_swizzle(__float_as_int(x), ((t) << 5) | 0x10))

// ---------------- K1: hidden0 = nf @ W_init + b_init ; copy; zero cnt --------
__global__ void __launch_bounds__(256) k_init(
        const float* __restrict__ nf, const float* __restrict__ Wini,
        const float* __restrict__ bini,
        float* __restrict__ hidden0, float* __restrict__ hid,
        int* __restrict__ cnt)
{
    int gtid = blockIdx.x * 256 + threadIdx.x;
    if (gtid <= N_NODES) cnt[gtid] = 0;
    int node = gtid >> 4;
    int j = gtid & 15;
    if (node >= N_NODES) return;

    const float4* nf4 = (const float4*)(nf + node * 32);
    float acc = bini[j];
#pragma unroll
    for (int g = 0; g < 8; ++g) {
        float4 v = nf4[g];
        acc = fmaf(v.x, Wini[(g*4+0)*16 + j], acc);
        acc = fmaf(v.y, Wini[(g*4+1)*16 + j], acc);
        acc = fmaf(v.z, Wini[(g*4+2)*16 + j], acc);
        acc = fmaf(v.w, Wini[(g*4+3)*16 + j], acc);
    }
    hidden0[node*16 + j] = acc;
    hid[node*16 + j] = acc;
}

// ---------------- CSR builds ----------------
__global__ void __launch_bounds__(256) k_hist(const int* __restrict__ idx,
                                              int* __restrict__ cnt)
{
    int e = blockIdx.x * 256 + threadIdx.x;
    if (e < N_EDGES) atomicAdd(&cnt[idx[e]], 1);
}

__global__ void __launch_bounds__(1024) k_scan(const int* __restrict__ cnt,
        int* __restrict__ row_ptr, int* __restrict__ cursor,
        float* __restrict__ out)
{
    __shared__ int sums[1024];
    int t = threadIdx.x;
    const int CH = (N_NODES + 1023) / 1024 + 1;   // 25 -> covers 25600
    int base = t * CH;
    int s = 0;
    for (int i = 0; i < CH; ++i) {
        int idx = base + i;
        if (idx < N_NODES) s += cnt[idx];
    }
    sums[t] = s;
    __syncthreads();
    for (int off = 1; off < 1024; off <<= 1) {
        int add = (t >= off) ? sums[t - off] : 0;
        __syncthreads();
        sums[t] += add;
        __syncthreads();
    }
    int run = sums[t] - s;
    for (int i = 0; i < CH; ++i) {
        int idx = base + i;
        if (idx < N_NODES) {
            row_ptr[idx] = run;
            cursor[idx]  = run;
            run += cnt[idx];
        }
    }
    if (t == 0) { row_ptr[N_NODES] = N_EDGES; out[0] = 0.0f; }
}

// sender-CSR: eids[pos] = original edge id, pos in sender-major order
__global__ void __launch_bounds__(256) k_scatter(const int* __restrict__ send,
        int* __restrict__ cursor, int* __restrict__ eids)
{
    int e = blockIdx.x * 256 + threadIdx.x;
    if (e < N_EDGES) {
        int pos = atomicAdd(&cursor[send[e]], 1);
        eids[pos] = e;
    }
}

// inverse map: rp[sender-order pos] = receiver-order position
__global__ void __launch_bounds__(256) k_rscatter(const int* __restrict__ eids,
        const int* __restrict__ recv,
        int* __restrict__ rcur, int* __restrict__ rp)
{
    int pos = blockIdx.x * 256 + threadIdx.x;
    if (pos < N_EDGES) {
        int r = recv[eids[pos]];
        rp[pos] = atomicAdd(&rcur[r], 1);
    }
}

// ---------------- K3: sender-major message compute, receiver-order store -----
// group (16 lanes) = one sender s; lane = message dim m.
// q[f] = sum_h We[f, m*16+h] * h[s,h]  (We is 17KB -> L1-resident)
// per out-edge: tmp[rp[i]*16+m] = qb + sum_f ef[eids[i],f]*q[f]
// (full 64B line per edge, scattered but no atomics; receiver-contiguous)
__global__ void __launch_bounds__(256) k_msg(
        const float* __restrict__ hid, const float* __restrict__ ef,
        const int* __restrict__ eids, const int* __restrict__ rp,
        const float* __restrict__ We, const float* __restrict__ be,
        const int* __restrict__ row_ptr,
        float* __restrict__ tmp)
{
    int gtid = blockIdx.x * 256 + threadIdx.x;
    int s = gtid >> 4;
    int m = gtid & 15;
    if (s >= N_NODES) return;

    float h[16];
    {
        const float4* h4 = (const float4*)(hid + s*16);
        float4 a = h4[0], b = h4[1], c = h4[2], d = h4[3];
        h[0]=a.x; h[1]=a.y; h[2]=a.z;  h[3]=a.w;
        h[4]=b.x; h[5]=b.y; h[6]=b.z;  h[7]=b.w;
        h[8]=c.x; h[9]=c.y; h[10]=c.z; h[11]=c.w;
        h[12]=d.x; h[13]=d.y; h[14]=d.z; h[15]=d.w;
    }
    float q[16];
#pragma unroll
    for (int f = 0; f < 16; ++f) {
        const float4* wf = (const float4*)(We + f*256 + m*16);
        float4 a = wf[0], b = wf[1], c = wf[2], d = wf[3];
        float acc;
        acc  = a.x*h[0]  + a.y*h[1]  + a.z*h[2]  + a.w*h[3];
        acc += b.x*h[4]  + b.y*h[5]  + b.z*h[6]  + b.w*h[7];
        acc += c.x*h[8]  + c.y*h[9]  + c.z*h[10] + c.w*h[11];
        acc += d.x*h[12] + d.y*h[13] + d.z*h[14] + d.w*h[15];
        q[f] = acc;
    }
    float qb;
    {
        const float4* bf = (const float4*)(be + m*16);
        float4 a = bf[0], b = bf[1], c = bf[2], d = bf[3];
        qb  = a.x*h[0]  + a.y*h[1]  + a.z*h[2]  + a.w*h[3];
        qb += b.x*h[4]  + b.y*h[5]  + b.z*h[6]  + b.w*h[7];
        qb += c.x*h[8]  + c.y*h[9]  + c.z*h[10] + c.w*h[11];
        qb += d.x*h[12] + d.y*h[13] + d.z*h[14] + d.w*h[15];
    }

    int beg = row_ptr[s];
    int end = row_ptr[s + 1];
    for (int i = beg; i < end; ++i) {
        int e = eids[i];
        int p = rp[i];
        const float4* e4 = (const float4*)(ef + (size_t)e*16);
        float4 e0 = e4[0], e1 = e4[1], e2 = e4[2], e3 = e4[3];
        float a = qb;
        a = fmaf(e0.x, q[0],  a);
        a = fmaf(e0.y, q[1],  a);
        a = fmaf(e0.z, q[2],  a);
        a = fmaf(e0.w, q[3],  a);
        a = fmaf(e1.x, q[4],  a);
        a = fmaf(e1.y, q[5],  a);
        a = fmaf(e1.z, q[6],  a);
        a = fmaf(e1.w, q[7],  a);
        a = fmaf(e2.x, q[8],  a);
        a = fmaf(e2.y, q[9],  a);
        a = fmaf(e2.z, q[10], a);
        a = fmaf(e2.w, q[11], a);
        a = fmaf(e3.x, q[12], a);
        a = fmaf(e3.y, q[13], a);
        a = fmaf(e3.z, q[14], a);
        a = fmaf(e3.w, q[15], a);
        tmp[(size_t)p*16 + m] = a;
    }
}

// ---------------- K4: coalesced gather + GRU (T=32), 2 scalars/lane ----------
// 16 lanes per node, lane j = GRU unit j. Node's messages are contiguous in
// tmp (receiver-CSR order): lane j sums dim j -> msg_own. Sequence inputs are
// broadcast per timestep from lane t via ds_swizzle; hn via XOR swizzle.
__global__ void __launch_bounds__(256) k_gru(
        const float* __restrict__ hid_in, const float* __restrict__ tmp,
        const int* __restrict__ rrow_ptr,
        const float* __restrict__ Wi, const float* __restrict__ Wh,
        const float* __restrict__ bi, const float* __restrict__ bh,
        float* __restrict__ hid_out)
{
    int gtid = blockIdx.x * 256 + threadIdx.x;
    int node = gtid >> 4;
    int j = gtid & 15;
    if (node >= N_NODES) return;

    // ---- coalesced gather: lane j sums dim j over contiguous in-edge lines --
    float msg_own = 0.0f;
    {
        int beg = rrow_ptr[node];
        int end = rrow_ptr[node + 1];
        const float* p = tmp + (size_t)beg * 16 + j;
        int d = end - beg;
        int i = 0;
        for (; i + 4 <= d; i += 4) {
            float a0 = p[(i+0)*16];
            float a1 = p[(i+1)*16];
            float a2 = p[(i+2)*16];
            float a3 = p[(i+3)*16];
            msg_own += (a0 + a1) + (a2 + a3);
        }
        for (; i < d; ++i) msg_own += p[i*16];
    }
    float h_own = hid_in[node*16 + j];

    float Wz[16], Wr[16], Wc[16];
#pragma unroll
    for (int k = 0; k < 16; ++k) {
        int l = j ^ k;
        Wz[k] = Wh[l*48 + j];
        Wr[k] = Wh[l*48 + 16 + j];
        Wc[k] = Wh[l*48 + 32 + j];
    }
    float Wiz = Wi[j], Wir = Wi[16+j], Wih = Wi[32+j];
    float cz   = bi[j] + bh[j];
    float cr   = bi[16+j] + bh[16+j];
    float bih_ = bi[32+j];
    float bhh_ = bh[32+j];

    float hn = 0.0f;

#define STEPK(k) { float v = SWZF(hn, k); \
        az = fmaf(v, Wz[k], az); ar = fmaf(v, Wr[k], ar); ac = fmaf(v, Wc[k], ac); }

#define GRUSTEP(XV) { \
        float xv = (XV); \
        float az = fmaf(xv, Wiz, cz); \
        float ar = fmaf(xv, Wir, cr); \
        float ac = bhh_; \
        az = fmaf(hn, Wz[0], az); \
        ar = fmaf(hn, Wr[0], ar); \
        ac = fmaf(hn, Wc[0], ac); \
        STEPK(1)  STEPK(2)  STEPK(3)  STEPK(4)  STEPK(5) \
        STEPK(6)  STEPK(7)  STEPK(8)  STEPK(9)  STEPK(10) \
        STEPK(11) STEPK(12) STEPK(13) STEPK(14) STEPK(15) \
        float z  = fast_sigmoid(az); \
        float r  = fast_sigmoid(ar); \
        float hc = fast_tanh(fmaf(xv, Wih, bih_) + r * ac); \
        hn = fmaf(z, hn - hc, hc); }

    // t = 0..15: x_t = hidden[node][t]
    GRUSTEP(BCAST16(h_own, 0))  GRUSTEP(BCAST16(h_own, 1))
    GRUSTEP(BCAST16(h_own, 2))  GRUSTEP(BCAST16(h_own, 3))
    GRUSTEP(BCAST16(h_own, 4))  GRUSTEP(BCAST16(h_own, 5))
    GRUSTEP(BCAST16(h_own, 6))  GRUSTEP(BCAST16(h_own, 7))
    GRUSTEP(BCAST16(h_own, 8))  GRUSTEP(BCAST16(h_own, 9))
    GRUSTEP(BCAST16(h_own, 10)) GRUSTEP(BCAST16(h_own, 11))
    GRUSTEP(BCAST16(h_own, 12)) GRUSTEP(BCAST16(h_own, 13))
    GRUSTEP(BCAST16(h_own, 14)) GRUSTEP(BCAST16(h_own, 15))
    // t = 16..31: x_t = messages[node][t-16]
    GRUSTEP(BCAST16(msg_own, 0))  GRUSTEP(BCAST16(msg_own, 1))
    GRUSTEP(BCAST16(msg_own, 2))  GRUSTEP(BCAST16(msg_own, 3))
    GRUSTEP(BCAST16(msg_own, 4))  GRUSTEP(BCAST16(msg_own, 5))
    GRUSTEP(BCAST16(msg_own, 6))  GRUSTEP(BCAST16(msg_own, 7))
    GRUSTEP(BCAST16(msg_own, 8))  GRUSTEP(BCAST16(msg_own, 9))
    GRUSTEP(BCAST16(msg_own, 10)) GRUSTEP(BCAST16(msg_own, 11))
    GRUSTEP(BCAST16(msg_own, 12)) GRUSTEP(BCAST16(msg_own, 13))
    GRUSTEP(BCAST16(msg_own, 14)) GRUSTEP(BCAST16(msg_own, 15))
#undef GRUSTEP
#undef STEPK

    hid_out[node*16 + j] = hn;
}

// ---------------- K5: readout ----------------
__global__ void __launch_bounds__(256) k_readout(
        const float* __restrict__ hid, const float* __restrict__ hid0,
        const float* __restrict__ Wri, const float* __restrict__ bri,
        const float* __restrict__ Wrj, const float* __restrict__ brj,
        float* __restrict__ out)
{
    int n = blockIdx.x * 256 + threadIdx.x;
    float val = 0.0f;
    if (n < N_NODES) {
        const float4* h4 = (const float4*)(hid + n * 16);
        const float4* g4 = (const float4*)(hid0 + n * 16);
        float iv = bri[0];
        float jv = brj[0];
#pragma unroll
        for (int g = 0; g < 4; ++g) {
            float4 h  = h4[g];
            float4 h0 = g4[g];
            iv = fmaf(h.x,  Wri[g*4+0], iv);  iv = fmaf(h.y,  Wri[g*4+1], iv);
            iv = fmaf(h.z,  Wri[g*4+2], iv);  iv = fmaf(h.w,  Wri[g*4+3], iv);
            iv = fmaf(h0.x, Wri[16+g*4+0], iv); iv = fmaf(h0.y, Wri[16+g*4+1], iv);
            iv = fmaf(h0.z, Wri[16+g*4+2], iv); iv = fmaf(h0.w, Wri[16+g*4+3], iv);
            jv = fmaf(h.x,  Wrj[g*4+0], jv);  jv = fmaf(h.y,  Wrj[g*4+1], jv);
            jv = fmaf(h.z,  Wrj[g*4+2], jv);  jv = fmaf(h.w,  Wrj[g*4+3], jv);
        }
        val = iv * jv;
    }
#pragma unroll
    for (int off = 32; off > 0; off >>= 1)
        val += __shfl_xor(val, off, 64);
    __shared__ float wsum[4];
    int w = threadIdx.x >> 6;
    if ((threadIdx.x & 63) == 0) wsum[w] = val;
    __syncthreads();
    if (threadIdx.x == 0)
        atomicAdd(out, wsum[0] + wsum[1] + wsum[2] + wsum[3]);
}

// ---------------- launch ----------------
extern "C" void kernel_launch(void* const* d_in, const int* in_sizes, int n_in,
                              void* d_out, int out_size, void* d_ws, size_t ws_size,
                              hipStream_t stream)
{
    const float* node_features = (const float*)d_in[0];
    const float* edge_features = (const float*)d_in[1];
    const float* W_init = (const float*)d_in[2];
    const float* b_init = (const float*)d_in[3];
    const float* W_edge = (const float*)d_in[4];
    const float* b_edge = (const float*)d_in[5];
    const float* Wi_gru = (const float*)d_in[6];
    const float* Wh_gru = (const float*)d_in[7];
    const float* bi_gru = (const float*)d_in[8];
    const float* bh_gru = (const float*)d_in[9];
    const float* W_ri = (const float*)d_in[10];
    const float* b_ri = (const float*)d_in[11];
    const float* W_rj = (const float*)d_in[12];
    const float* b_rj = (const float*)d_in[13];
    const int* receivers = (const int*)d_in[14];
    const int* senders   = (const int*)d_in[15];
    float* out = (float*)d_out;

    // workspace carve: floats then ints; ~34.2 MB total
    float* fb      = (float*)d_ws;
    float* hidden0 = fb;                 // 400000
    float* hidA    = fb + 400000;        // 400000
    float* hidB    = fb + 800000;        // 400000
    float* tmp     = fb + 1200000;       // 6400000 (E*16, receiver-order msgs)
    int* ib       = (int*)(fb + 7600000);
    int* cnt      = ib;                  // 25024
    int* row_ptr  = ib + 25024;          // 25024
    int* cursor   = ib + 50048;          // 25024
    int* rcnt     = ib + 75072;          // 25024
    int* rrow_ptr = ib + 100096;         // 25024
    int* rcur     = ib + 125120;         // 25024
    int* eids     = ib + 150144;         // 400000
    int* rp       = ib + 550144;         // 400000

    dim3 b256(256);
    int grid_n16 = (N_NODES * 16 + 255) / 256;   // 1563
    int grid_e   = (N_EDGES + 255) / 256;        // 1563
    int grid_n   = (N_NODES + 255) / 256;        // 98

    hipMemsetAsync(rcnt, 0, 25024 * sizeof(int), stream);
    k_init<<<grid_n16, b256, 0, stream>>>(node_features, W_init, b_init,
                                          hidden0, hidA, cnt);
    k_hist<<<grid_e, b256, 0, stream>>>(senders, cnt);
    k_scan<<<1, 1024, 0, stream>>>(cnt, row_ptr, cursor, out);
    k_scatter<<<grid_e, b256, 0, stream>>>(senders, cursor, eids);
    k_hist<<<grid_e, b256, 0, stream>>>(receivers, rcnt);
    k_scan<<<1, 1024, 0, stream>>>(rcnt, rrow_ptr, rcur, out);
    k_rscatter<<<grid_e, b256, 0, stream>>>(eids, receivers, rcur, rp);

    float* hin = hidA;
    float* hout = hidB;
    for (int it = 0; it < 3; ++it) {
        k_msg<<<grid_n16, b256, 0, stream>>>(hin, edge_features, eids, rp,
                                             W_edge, b_edge, row_ptr, tmp);
        k_gru<<<grid_n16, b256, 0, stream>>>(hin, tmp, rrow_ptr,
                                             Wi_gru, Wh_gru, bi_gru, bh_gru, hout);
        float* t = hin; hin = hout; hout = t;
    }

    k_readout<<<grid_n, b256, 0, stream>>>(hin, hidden0, W_ri, b_ri, W_rj, b_rj, out);
}

// Round 3
// 576.683 us; speedup vs baseline: 1.1084x; 1.0076x over previous
//
#include <hip/hip_runtime.h>

#define N_NODES 25000
#define N_EDGES 400000

// ---------------- fast transcendentals (fp32, ~2ulp) ----------------
__device__ __forceinline__ float fast_sigmoid(float x) {
    return __builtin_amdgcn_rcpf(1.0f + __expf(-x));
}
__device__ __forceinline__ float fast_tanh(float x) {
    return 1.0f - 2.0f * __builtin_amdgcn_rcpf(__expf(2.0f * x) + 1.0f);
}

// lane j receives value from lane j^k within its 32-lane half (k<16 keeps it
// inside the 16-lane node group). BitMode offset = (xor<<10)|(or<<5)|and.
#define SWZF(x, k) __int_as_float(__builtin_amdgcn_ds_swizzle(__float_as_int(x), ((k) << 10) | 0x1F))
// broadcast lane t of each 16-lane group: src = (lane & 0x10) | t
#define BCAST16(x, t) __int_as_float(__builtin_amdgcn_ds_swizzle(__float_as_int(x), ((t) << 5) | 0x10))

// ---------------- K1: hidden0 = nf @ W_init + b_init ; copy; zero cnt --------
__global__ void __launch_bounds__(256) k_init(
        const float* __restrict__ nf, const float* __restrict__ Wini,
        const float* __restrict__ bini,
        float* __restrict__ hidden0, float* __restrict__ hid,
        int* __restrict__ cnt)
{
    int gtid = blockIdx.x * 256 + threadIdx.x;
    if (gtid <= N_NODES) cnt[gtid] = 0;
    int node = gtid >> 4;
    int j = gtid & 15;
    if (node >= N_NODES) return;

    const float4* nf4 = (const float4*)(nf + node * 32);
    float acc = bini[j];
#pragma unroll
    for (int g = 0; g < 8; ++g) {
        float4 v = nf4[g];
        acc = fmaf(v.x, Wini[(g*4+0)*16 + j], acc);
        acc = fmaf(v.y, Wini[(g*4+1)*16 + j], acc);
        acc = fmaf(v.z, Wini[(g*4+2)*16 + j], acc);
        acc = fmaf(v.w, Wini[(g*4+3)*16 + j], acc);
    }
    hidden0[node*16 + j] = acc;
    hid[node*16 + j] = acc;
}

// ---------------- CSR builds ----------------
__global__ void __launch_bounds__(256) k_hist(const int* __restrict__ idx,
                                              int* __restrict__ cnt)
{
    int e = blockIdx.x * 256 + threadIdx.x;
    if (e < N_EDGES) atomicAdd(&cnt[idx[e]], 1);
}

__global__ void __launch_bounds__(1024) k_scan(const int* __restrict__ cnt,
        int* __restrict__ row_ptr, int* __restrict__ cursor,
        float* __restrict__ out)
{
    __shared__ int sums[1024];
    int t = threadIdx.x;
    const int CH = (N_NODES + 1023) / 1024 + 1;   // 25 -> covers 25600
    int base = t * CH;
    int s = 0;
    for (int i = 0; i < CH; ++i) {
        int idx = base + i;
        if (idx < N_NODES) s += cnt[idx];
    }
    sums[t] = s;
    __syncthreads();
    for (int off = 1; off < 1024; off <<= 1) {
        int add = (t >= off) ? sums[t - off] : 0;
        __syncthreads();
        sums[t] += add;
        __syncthreads();
    }
    int run = sums[t] - s;
    for (int i = 0; i < CH; ++i) {
        int idx = base + i;
        if (idx < N_NODES) {
            row_ptr[idx] = run;
            cursor[idx]  = run;
            run += cnt[idx];
        }
    }
    if (t == 0) { row_ptr[N_NODES] = N_EDGES; out[0] = 0.0f; }
}

// sender-CSR: eids[pos] = original edge id, pos in sender-major order
__global__ void __launch_bounds__(256) k_scatter(const int* __restrict__ send,
        int* __restrict__ cursor, int* __restrict__ eids)
{
    int e = blockIdx.x * 256 + threadIdx.x;
    if (e < N_EDGES) {
        int pos = atomicAdd(&cursor[send[e]], 1);
        eids[pos] = e;
    }
}

// inverse map: rp[sender-order pos] = receiver-order position
__global__ void __launch_bounds__(256) k_rscatter(const int* __restrict__ eids,
        const int* __restrict__ recv,
        int* __restrict__ rcur, int* __restrict__ rp)
{
    int pos = blockIdx.x * 256 + threadIdx.x;
    if (pos < N_EDGES) {
        int r = recv[eids[pos]];
        rp[pos] = atomicAdd(&rcur[r], 1);
    }
}

// efp[pos,:] = ef[eids[pos],:]  (edge features into sender-CSR order; once)
__global__ void __launch_bounds__(256) k_permute(const float* __restrict__ ef,
        const int* __restrict__ eids, float* __restrict__ efp)
{
    int gtid = blockIdx.x * 256 + threadIdx.x;
    int pos = gtid >> 4;
    int c = gtid & 15;
    if (pos < N_EDGES) efp[(size_t)pos*16 + c] = ef[(size_t)eids[pos]*16 + c];
}

// ---------------- K3: sender-major message compute, receiver-order store -----
// group (16 lanes) = one sender s; lane = message dim m.
// q[f] = sum_h We[f, m*16+h] * h[s,h]  (We is 17KB -> L1-resident)
// Streaming reads: efp (sequential), rp (sequential).
// Scattered full-line stores: tmp[rp[i]*16+m] (receiver-contiguous lines).
__global__ void __launch_bounds__(256) k_msg(
        const float* __restrict__ hid, const float* __restrict__ efp,
        const int* __restrict__ rp,
        const float* __restrict__ We, const float* __restrict__ be,
        const int* __restrict__ row_ptr,
        float* __restrict__ tmp)
{
    int gtid = blockIdx.x * 256 + threadIdx.x;
    int s = gtid >> 4;
    int m = gtid & 15;
    if (s >= N_NODES) return;

    float h[16];
    {
        const float4* h4 = (const float4*)(hid + s*16);
        float4 a = h4[0], b = h4[1], c = h4[2], d = h4[3];
        h[0]=a.x; h[1]=a.y; h[2]=a.z;  h[3]=a.w;
        h[4]=b.x; h[5]=b.y; h[6]=b.z;  h[7]=b.w;
        h[8]=c.x; h[9]=c.y; h[10]=c.z; h[11]=c.w;
        h[12]=d.x; h[13]=d.y; h[14]=d.z; h[15]=d.w;
    }
    float q[16];
#pragma unroll
    for (int f = 0; f < 16; ++f) {
        const float4* wf = (const float4*)(We + f*256 + m*16);
        float4 a = wf[0], b = wf[1], c = wf[2], d = wf[3];
        float acc;
        acc  = a.x*h[0]  + a.y*h[1]  + a.z*h[2]  + a.w*h[3];
        acc += b.x*h[4]  + b.y*h[5]  + b.z*h[6]  + b.w*h[7];
        acc += c.x*h[8]  + c.y*h[9]  + c.z*h[10] + c.w*h[11];
        acc += d.x*h[12] + d.y*h[13] + d.z*h[14] + d.w*h[15];
        q[f] = acc;
    }
    float qb;
    {
        const float4* bf = (const float4*)(be + m*16);
        float4 a = bf[0], b = bf[1], c = bf[2], d = bf[3];
        qb  = a.x*h[0]  + a.y*h[1]  + a.z*h[2]  + a.w*h[3];
        qb += b.x*h[4]  + b.y*h[5]  + b.z*h[6]  + b.w*h[7];
        qb += c.x*h[8]  + c.y*h[9]  + c.z*h[10] + c.w*h[11];
        qb += d.x*h[12] + d.y*h[13] + d.z*h[14] + d.w*h[15];
    }

    int beg = row_ptr[s];
    int end = row_ptr[s + 1];
    for (int i = beg; i < end; ++i) {
        int p = rp[i];
        const float4* e4 = (const float4*)(efp + (size_t)i*16);
        float4 e0 = e4[0], e1 = e4[1], e2 = e4[2], e3 = e4[3];
        float a = qb;
        a = fmaf(e0.x, q[0],  a);
        a = fmaf(e0.y, q[1],  a);
        a = fmaf(e0.z, q[2],  a);
        a = fmaf(e0.w, q[3],  a);
        a = fmaf(e1.x, q[4],  a);
        a = fmaf(e1.y, q[5],  a);
        a = fmaf(e1.z, q[6],  a);
        a = fmaf(e1.w, q[7],  a);
        a = fmaf(e2.x, q[8],  a);
        a = fmaf(e2.y, q[9],  a);
        a = fmaf(e2.z, q[10], a);
        a = fmaf(e2.w, q[11], a);
        a = fmaf(e3.x, q[12], a);
        a = fmaf(e3.y, q[13], a);
        a = fmaf(e3.z, q[14], a);
        a = fmaf(e3.w, q[15], a);
        tmp[(size_t)p*16 + m] = a;
    }
}

// ---------------- K4: coalesced gather + GRU (T=32), 2 scalars/lane ----------
// 16 lanes per node, lane j = GRU unit j. Node's messages are contiguous in
// tmp (receiver-CSR order): lane j sums dim j -> msg_own. Sequence inputs are
// broadcast per timestep from lane t via ds_swizzle; hn via XOR swizzle.
__global__ void __launch_bounds__(256) k_gru(
        const float* __restrict__ hid_in, const float* __restrict__ tmp,
        const int* __restrict__ rrow_ptr,
        const float* __restrict__ Wi, const float* __restrict__ Wh,
        const float* __restrict__ bi, const float* __restrict__ bh,
        float* __restrict__ hid_out)
{
    int gtid = blockIdx.x * 256 + threadIdx.x;
    int node = gtid >> 4;
    int j = gtid & 15;
    if (node >= N_NODES) return;

    // ---- coalesced gather: lane j sums dim j over contiguous in-edge lines --
    float msg_own = 0.0f;
    {
        int beg = rrow_ptr[node];
        int end = rrow_ptr[node + 1];
        const float* p = tmp + (size_t)beg * 16 + j;
        int d = end - beg;
        int i = 0;
        for (; i + 4 <= d; i += 4) {
            float a0 = p[(i+0)*16];
            float a1 = p[(i+1)*16];
            float a2 = p[(i+2)*16];
            float a3 = p[(i+3)*16];
            msg_own += (a0 + a1) + (a2 + a3);
        }
        for (; i < d; ++i) msg_own += p[i*16];
    }
    float h_own = hid_in[node*16 + j];

    float Wz[16], Wr[16], Wc[16];
#pragma unroll
    for (int k = 0; k < 16; ++k) {
        int l = j ^ k;
        Wz[k] = Wh[l*48 + j];
        Wr[k] = Wh[l*48 + 16 + j];
        Wc[k] = Wh[l*48 + 32 + j];
    }
    float Wiz = Wi[j], Wir = Wi[16+j], Wih = Wi[32+j];
    float cz   = bi[j] + bh[j];
    float cr   = bi[16+j] + bh[16+j];
    float bih_ = bi[32+j];
    float bhh_ = bh[32+j];

    float hn = 0.0f;

#define STEPK(k) { float v = SWZF(hn, k); \
        az = fmaf(v, Wz[k], az); ar = fmaf(v, Wr[k], ar); ac = fmaf(v, Wc[k], ac); }

#define GRUSTEP(XV) { \
        float xv = (XV); \
        float az = fmaf(xv, Wiz, cz); \
        float ar = fmaf(xv, Wir, cr); \
        float ac = bhh_; \
        az = fmaf(hn, Wz[0], az); \
        ar = fmaf(hn, Wr[0], ar); \
        ac = fmaf(hn, Wc[0], ac); \
        STEPK(1)  STEPK(2)  STEPK(3)  STEPK(4)  STEPK(5) \
        STEPK(6)  STEPK(7)  STEPK(8)  STEPK(9)  STEPK(10) \
        STEPK(11) STEPK(12) STEPK(13) STEPK(14) STEPK(15) \
        float z  = fast_sigmoid(az); \
        float r  = fast_sigmoid(ar); \
        float hc = fast_tanh(fmaf(xv, Wih, bih_) + r * ac); \
        hn = fmaf(z, hn - hc, hc); }

    // t = 0..15: x_t = hidden[node][t]
    GRUSTEP(BCAST16(h_own, 0))  GRUSTEP(BCAST16(h_own, 1))
    GRUSTEP(BCAST16(h_own, 2))  GRUSTEP(BCAST16(h_own, 3))
    GRUSTEP(BCAST16(h_own, 4))  GRUSTEP(BCAST16(h_own, 5))
    GRUSTEP(BCAST16(h_own, 6))  GRUSTEP(BCAST16(h_own, 7))
    GRUSTEP(BCAST16(h_own, 8))  GRUSTEP(BCAST16(h_own, 9))
    GRUSTEP(BCAST16(h_own, 10)) GRUSTEP(BCAST16(h_own, 11))
    GRUSTEP(BCAST16(h_own, 12)) GRUSTEP(BCAST16(h_own, 13))
    GRUSTEP(BCAST16(h_own, 14)) GRUSTEP(BCAST16(h_own, 15))
    // t = 16..31: x_t = messages[node][t-16]
    GRUSTEP(BCAST16(msg_own, 0))  GRUSTEP(BCAST16(msg_own, 1))
    GRUSTEP(BCAST16(msg_own, 2))  GRUSTEP(BCAST16(msg_own, 3))
    GRUSTEP(BCAST16(msg_own, 4))  GRUSTEP(BCAST16(msg_own, 5))
    GRUSTEP(BCAST16(msg_own, 6))  GRUSTEP(BCAST16(msg_own, 7))
    GRUSTEP(BCAST16(msg_own, 8))  GRUSTEP(BCAST16(msg_own, 9))
    GRUSTEP(BCAST16(msg_own, 10)) GRUSTEP(BCAST16(msg_own, 11))
    GRUSTEP(BCAST16(msg_own, 12)) GRUSTEP(BCAST16(msg_own, 13))
    GRUSTEP(BCAST16(msg_own, 14)) GRUSTEP(BCAST16(msg_own, 15))
#undef GRUSTEP
#undef STEPK

    hid_out[node*16 + j] = hn;
}

// ---------------- K5: readout ----------------
__global__ void __launch_bounds__(256) k_readout(
        const float* __restrict__ hid, const float* __restrict__ hid0,
        const float* __restrict__ Wri, const float* __restrict__ bri,
        const float* __restrict__ Wrj, const float* __restrict__ brj,
        float* __restrict__ out)
{
    int n = blockIdx.x * 256 + threadIdx.x;
    float val = 0.0f;
    if (n < N_NODES) {
        const float4* h4 = (const float4*)(hid + n * 16);
        const float4* g4 = (const float4*)(hid0 + n * 16);
        float iv = bri[0];
        float jv = brj[0];
#pragma unroll
        for (int g = 0; g < 4; ++g) {
            float4 h  = h4[g];
            float4 h0 = g4[g];
            iv = fmaf(h.x,  Wri[g*4+0], iv);  iv = fmaf(h.y,  Wri[g*4+1], iv);
            iv = fmaf(h.z,  Wri[g*4+2], iv);  iv = fmaf(h.w,  Wri[g*4+3], iv);
            iv = fmaf(h0.x, Wri[16+g*4+0], iv); iv = fmaf(h0.y, Wri[16+g*4+1], iv);
            iv = fmaf(h0.z, Wri[16+g*4+2], iv); iv = fmaf(h0.w, Wri[16+g*4+3], iv);
            jv = fmaf(h.x,  Wrj[g*4+0], jv);  jv = fmaf(h.y,  Wrj[g*4+1], jv);
            jv = fmaf(h.z,  Wrj[g*4+2], jv);  jv = fmaf(h.w,  Wrj[g*4+3], jv);
        }
        val = iv * jv;
    }
#pragma unroll
    for (int off = 32; off > 0; off >>= 1)
        val += __shfl_xor(val, off, 64);
    __shared__ float wsum[4];
    int w = threadIdx.x >> 6;
    if ((threadIdx.x & 63) == 0) wsum[w] = val;
    __syncthreads();
    if (threadIdx.x == 0)
        atomicAdd(out, wsum[0] + wsum[1] + wsum[2] + wsum[3]);
}

// ---------------- launch ----------------
extern "C" void kernel_launch(void* const* d_in, const int* in_sizes, int n_in,
                              void* d_out, int out_size, void* d_ws, size_t ws_size,
                              hipStream_t stream)
{
    const float* node_features = (const float*)d_in[0];
    const float* edge_features = (const float*)d_in[1];
    const float* W_init = (const float*)d_in[2];
    const float* b_init = (const float*)d_in[3];
    const float* W_edge = (const float*)d_in[4];
    const float* b_edge = (const float*)d_in[5];
    const float* Wi_gru = (const float*)d_in[6];
    const float* Wh_gru = (const float*)d_in[7];
    const float* bi_gru = (const float*)d_in[8];
    const float* bh_gru = (const float*)d_in[9];
    const float* W_ri = (const float*)d_in[10];
    const float* b_ri = (const float*)d_in[11];
    const float* W_rj = (const float*)d_in[12];
    const float* b_rj = (const float*)d_in[13];
    const int* receivers = (const int*)d_in[14];
    const int* senders   = (const int*)d_in[15];
    float* out = (float*)d_out;

    // workspace carve: floats then ints; ~60 MB total
    float* fb      = (float*)d_ws;
    float* hidden0 = fb;                 // 400000
    float* hidA    = fb + 400000;        // 400000
    float* hidB    = fb + 800000;        // 400000
    float* tmp     = fb + 1200000;       // 6400000 (E*16, receiver-order msgs)
    float* efp     = fb + 7600000;       // 6400000 (E*16, sender-order feats)
    int* ib       = (int*)(fb + 14000000);
    int* cnt      = ib;                  // 25024
    int* row_ptr  = ib + 25024;          // 25024
    int* cursor   = ib + 50048;          // 25024
    int* rcnt     = ib + 75072;          // 25024
    int* rrow_ptr = ib + 100096;         // 25024
    int* rcur     = ib + 125120;         // 25024
    int* eids     = ib + 150144;         // 400000
    int* rp       = ib + 550144;         // 400000

    dim3 b256(256);
    int grid_n16 = (N_NODES * 16 + 255) / 256;   // 1563
    int grid_e   = (N_EDGES + 255) / 256;        // 1563
    int grid_e16 = (N_EDGES * 16 + 255) / 256;   // 25000
    int grid_n   = (N_NODES + 255) / 256;        // 98

    hipMemsetAsync(rcnt, 0, 25024 * sizeof(int), stream);
    k_init<<<grid_n16, b256, 0, stream>>>(node_features, W_init, b_init,
                                          hidden0, hidA, cnt);
    k_hist<<<grid_e, b256, 0, stream>>>(senders, cnt);
    k_scan<<<1, 1024, 0, stream>>>(cnt, row_ptr, cursor, out);
    k_scatter<<<grid_e, b256, 0, stream>>>(senders, cursor, eids);
    k_hist<<<grid_e, b256, 0, stream>>>(receivers, rcnt);
    k_scan<<<1, 1024, 0, stream>>>(rcnt, rrow_ptr, rcur, out);
    k_rscatter<<<grid_e, b256, 0, stream>>>(eids, receivers, rcur, rp);
    k_permute<<<grid_e16, b256, 0, stream>>>(edge_features, eids, efp);

    float* hin = hidA;
    float* hout = hidB;
    for (int it = 0; it < 3; ++it) {
        k_msg<<<grid_n16, b256, 0, stream>>>(hin, efp, rp,
                                             W_edge, b_edge, row_ptr, tmp);
        k_gru<<<grid_n16, b256, 0, stream>>>(hin, tmp, rrow_ptr,
                                             Wi_gru, Wh_gru, bi_gru, bh_gru, hout);
        float* t = hin; hin = hout; hout = t;
    }

    k_readout<<<grid_n, b256, 0, stream>>>(hin, hidden0, W_ri, b_ri, W_rj, b_rj, out);
}